// Round 16
// baseline (341.654 us; speedup 1.0000x reference)
//
#include <hip/hip_runtime.h>
#include <hip/hip_bf16.h>
#include <hip/hip_fp8.h>
#include <math.h>

// GCN. CSR via block-privatized 2-pass counting sort; fp8-e4m3 gathered arrays.
// r16: k_z occupancy fix — r15 PMC: VGPR=64 (weights NOT resident, re-loaded
// from L1 per row) + grid 1024 = 4 blocks/CU = 38% occupancy -> latency bound
// at 55us vs ~22us VALU floor. Max co-residency is 8 blocks/CU at 256 thr;
// grid k_z 1024->2048, k_weight 1024->2048. Convs unchanged (at TA request
// floor per r14/r15).

#define F 64
#define OUTF 32
#define PB 128            // edge-partition blocks (privatized sort)
#define LEDGE 5632        // per-bucket LDS capacity (mean 4096)
#define BN_INV 0.9999950000374997f  // rsqrt(1 + 1e-5)
#define ESC_X 32.0f
#define IESC_X 0.03125f
#define ESC_Z 64.0f
#define IESC_Z 0.015625f

__device__ __forceinline__ unsigned fenc(float f) {
    unsigned u = __float_as_uint(f);
    return (u & 0x80000000u) ? ~u : (u | 0x80000000u);
}
__device__ __forceinline__ float fdec(unsigned e) {
    return (e & 0x80000000u) ? __uint_as_float(e & 0x7fffffffu) : __uint_as_float(~e);
}
__device__ __forceinline__ unsigned short f2bf(float f) {  // RNE
    unsigned u = __float_as_uint(f);
    return (unsigned short)((u + 0x7fffu + ((u >> 16) & 1u)) >> 16);
}
__device__ __forceinline__ float bf2f(unsigned short h) {
    return __uint_as_float((unsigned)h << 16);
}

#if __has_builtin(__builtin_amdgcn_cvt_f32_fp8) && __has_builtin(__builtin_amdgcn_cvt_pk_fp8_f32)
__device__ __forceinline__ float4 fp8x4(unsigned v) {
    return make_float4(__builtin_amdgcn_cvt_f32_fp8((int)v, 0),
                       __builtin_amdgcn_cvt_f32_fp8((int)v, 1),
                       __builtin_amdgcn_cvt_f32_fp8((int)v, 2),
                       __builtin_amdgcn_cvt_f32_fp8((int)v, 3));
}
__device__ __forceinline__ unsigned fp8pk4(float a, float b, float c, float d) {
    int r = __builtin_amdgcn_cvt_pk_fp8_f32(a, b, 0, false);
    r = __builtin_amdgcn_cvt_pk_fp8_f32(c, d, r, true);
    return (unsigned)r;
}
__device__ __forceinline__ unsigned char fp8enc1(float a) {
    return (unsigned char)(__builtin_amdgcn_cvt_pk_fp8_f32(a, a, 0, false) & 0xff);
}
#else
__device__ __forceinline__ float fp8d1(unsigned char b) {
    __hip_fp8_e4m3 v; v.__x = (__hip_fp8_storage_t)b; return (float)v;
}
__device__ __forceinline__ float4 fp8x4(unsigned v) {
    return make_float4(fp8d1(v & 255u), fp8d1((v >> 8) & 255u), fp8d1((v >> 16) & 255u), fp8d1((v >> 24) & 255u));
}
__device__ __forceinline__ unsigned char fp8enc1(float a) {
    return (unsigned char)__hip_fp8_e4m3(a).__x;
}
__device__ __forceinline__ unsigned fp8pk4(float a, float b, float c, float d) {
    return (unsigned)fp8enc1(a) | ((unsigned)fp8enc1(b) << 8) | ((unsigned)fp8enc1(c) << 16) | ((unsigned)fp8enc1(d) << 24);
}
#endif

// red layout: [0..31] acc_c, [32] esum, [33] min-enc(uint), [34] max-enc(uint)

// blocks 0..PB-1: histogram; blocks PB..PB+7: head-weight fusion + red init
__global__ __launch_bounds__(256) void k_hist(const int* __restrict__ dst, int* __restrict__ hist,
                                              int E, int NBK,
                                              const float* __restrict__ W2, const float* __restrict__ b2,
                                              const float* __restrict__ l2w, const float* __restrict__ l2b,
                                              float* __restrict__ w2l2, float* __restrict__ b2l2,
                                              float* __restrict__ red) {
    __shared__ int lh[512];
    int t = threadIdx.x, blk = blockIdx.x;
    if (blk >= PB) {  // fuse part
        int tt = (blk - PB) * 256 + t;  // 0..2047
        int k = tt >> 5, cc = tt & 31;
        float o = 0.0f;
        for (int j = 0; j < F; j++) o += W2[k * F + j] * l2w[j * OUTF + cc];
        w2l2[k * OUTF + cc] = o;
        if (tt < OUTF) {
            float b = l2b[tt];
            for (int j = 0; j < F; j++) b += b2[j] * l2w[j * OUTF + tt];
            b2l2[tt] = b;
        }
        if (tt < 33) red[tt] = 0.0f;
        if (tt == 33) ((unsigned*)red)[33] = 0xFFFFFFFFu;
        if (tt == 34) ((unsigned*)red)[34] = 0u;
        return;
    }
    for (int b = t; b < NBK; b += 256) lh[b] = 0;
    __syncthreads();
    int chunk = (E + PB - 1) / PB;
    int beg = blk * chunk, end = min(beg + chunk, E);
    for (int e = beg + t; e < end; e += 256) atomicAdd(&lh[dst[e] >> 8], 1);
    __syncthreads();
    for (int b = t; b < NBK; b += 256) hist[blk * NBK + b] = lh[b];  // dense coalesced
}

// per-bucket exclusive scan across the PB blocks (one block per bucket)
__global__ __launch_bounds__(PB) void k_hscan1(int* __restrict__ hist, int* __restrict__ btot, int NBK) {
    __shared__ int s[PB];
    int b = blockIdx.x, t = threadIdx.x;
    int v = hist[t * NBK + b];
    s[t] = v;
    __syncthreads();
    for (int off = 1; off < PB; off <<= 1) {
        int u = (t >= off) ? s[t - off] : 0;
        __syncthreads();
        s[t] += u;
        __syncthreads();
    }
    hist[t * NBK + b] = s[t] - v;  // exclusive within bucket
    if (t == PB - 1) btot[b] = s[t];
}

// scan bucket totals -> bbase (1 block; NBK <= 512)
__global__ void k_hscan2(const int* __restrict__ btot, int* __restrict__ bbase, int NBK) {
    __shared__ int s[512];
    int t = threadIdx.x;
    int v = (t < NBK) ? btot[t] : 0;
    s[t] = v;
    __syncthreads();
    for (int off = 1; off < 512; off <<= 1) {
        int u = (t >= off) ? s[t - off] : 0;
        __syncthreads();
        s[t] += u;
        __syncthreads();
    }
    if (t < NBK) {
        bbase[t] = s[t] - v;
        if (t == NBK - 1) bbase[NBK] = s[t];
    }
}

// pass 2: private cursors in LDS (hist offset + bucket base); single-writer lines
__global__ __launch_bounds__(256) void k_place(const int* __restrict__ src, const int* __restrict__ dst,
                                               const int* __restrict__ hist, const int* __restrict__ bbase,
                                               unsigned* __restrict__ bucketArr, int E, int NBK) {
    __shared__ int cur[512];
    int t = threadIdx.x, blk = blockIdx.x;
    for (int b = t; b < NBK; b += 256) cur[b] = hist[blk * NBK + b] + bbase[b];
    __syncthreads();
    int chunk = (E + PB - 1) / PB;
    int beg = blk * chunk, end = min(beg + chunk, E);
    for (int e = beg + t; e < end; e += 256) {
        int d = dst[e], sidx = src[e];
        int p = atomicAdd(&cur[d >> 8], 1);
        bucketArr[p] = ((unsigned)sidx << 8) | (unsigned)(d & 255);
    }
}

// one block per bucket: LDS count -> scan -> place -> fused x-prescale.
// Emits CSR eidx + meta{beg,deg,dinv} + xq = fp8(x*dinv*32).
__global__ __launch_bounds__(256) void k_binsort(const unsigned* __restrict__ bucketArr,
                                                 const int* __restrict__ bbase,
                                                 int* __restrict__ eidx, int4* __restrict__ meta,
                                                 const float4* __restrict__ x4, unsigned* __restrict__ xq, int N) {
    __shared__ unsigned ledge[LEDGE];
    __shared__ int lcnt[256], lofs[256], lcur[256], lscan[256];
    __shared__ float ldinv[256];
    int b = blockIdx.x, t = threadIdx.x;
    int gb = bbase[b];
    int count = min(bbase[b + 1] - gb, LEDGE);
    for (int j = t; j < count; j += 256) ledge[j] = bucketArr[gb + j];
    lcnt[t] = 0;
    __syncthreads();
    for (int j = t; j < count; j += 256) atomicAdd(&lcnt[ledge[j] & 255u], 1);
    __syncthreads();
    int deg = lcnt[t];
    lscan[t] = deg;
    __syncthreads();
    for (int off = 1; off < 256; off <<= 1) {
        int u = (t >= off) ? lscan[t - off] : 0;
        __syncthreads();
        lscan[t] += u;
        __syncthreads();
    }
    lofs[t] = lscan[t] - deg;  // exclusive
    lcur[t] = 0;
    int node = (b << 8) + t;
    float di = rsqrtf((float)deg + 1.0f);
    ldinv[t] = di;
    if (node < N) meta[node] = make_int4(gb + lofs[t], deg, __float_as_int(di), 0);
    __syncthreads();
    for (int j = t; j < count; j += 256) {
        unsigned v = ledge[j];
        int loc = (int)(v & 255u);
        int p = atomicAdd(&lcur[loc], 1);
        eidx[gb + lofs[loc] + p] = (int)(v >> 8);  // single-writer 16KB window
    }
    // fused prescale for this bucket's 256 nodes (coalesced: 16 threads/node)
    for (int idx = t; idx < 256 * 16; idx += 256) {
        int nd = (b << 8) + (idx >> 4);
        if (nd < N) {
            float d2 = ldinv[idx >> 4] * ESC_X;
            float4 v = x4[(size_t)nd * 16 + (idx & 15)];
            xq[(size_t)nd * 16 + (idx & 15)] = fp8pk4(v.x * d2, v.y * d2, v.z * d2, v.w * d2);
        }
    }
}

// conv1: t1 = f32( dinv/32 * (sum_nbr xq[s] + xq[i]) ).
// wave = 8 nodes x 8 lanes x 8ch (uint2 = 8 fp8 per lane). Exact-fit grid: 1 batch/wave.
__global__ __launch_bounds__(256, 4) void k_conv1agg(const uint2* __restrict__ xq2,
                                                     const int4* __restrict__ meta,
                                                     const int* __restrict__ eidx,
                                                     float* __restrict__ t1, int N, int Em1) {
    int tid = threadIdx.x, wave = tid >> 6, lane = tid & 63;
    int g = lane >> 3, gl = lane & 7, gbase = lane & 56;
    int i = (blockIdx.x * 4 + wave) * 8 + g;
    int iclamp = min(i, N - 1);
    int4 m = meta[iclamp];
    int beg = m.x;
    int dcnt = (i < N) ? m.y : 0;
    float dis = __int_as_float(m.z) * IESC_X;
    int ss0 = eidx[min(beg + gl, Em1)];
    int ss1 = eidx[min(beg + 8 + gl, Em1)];
    int ss2 = eidx[min(beg + 16 + gl, Em1)];
    int ss3 = eidx[min(beg + 24 + gl, Em1)];
    uint2 selfv = xq2[(size_t)iclamp * 8 + gl];
    uint2 vbuf[32];
#pragma unroll
    for (int k = 0; k < 32; k++) {
        int sreg = (k < 8) ? ss0 : (k < 16) ? ss1 : (k < 24) ? ss2 : ss3;
        int sv = __shfl(sreg, gbase + (k & 7), 64);
        sv = (k < dcnt) ? sv : iclamp;  // invalid slot -> own row (hot line)
        vbuf[k] = xq2[(size_t)sv * 8 + gl];
    }
    __builtin_amdgcn_sched_barrier(0);  // pin: full burst before first use
    float4 aA0 = fp8x4(selfv.x), aB0 = fp8x4(selfv.y);
    float4 aA1 = make_float4(0.f, 0.f, 0.f, 0.f), aB1 = aA1;
#pragma unroll
    for (int k = 0; k < 32; k++) {
        if (k < dcnt) {
            float4 vA = fp8x4(vbuf[k].x), vB = fp8x4(vbuf[k].y);
            if (k & 1) {
                aA1.x += vA.x; aA1.y += vA.y; aA1.z += vA.z; aA1.w += vA.w;
                aB1.x += vB.x; aB1.y += vB.y; aB1.z += vB.z; aB1.w += vB.w;
            } else {
                aA0.x += vA.x; aA0.y += vA.y; aA0.z += vA.z; aA0.w += vA.w;
                aB0.x += vB.x; aB0.y += vB.y; aB0.z += vB.z; aB0.w += vB.w;
            }
        }
    }
    for (int base = 32; base < dcnt; base += 8) {  // rare tail
        int j = base + gl;
        int ss = eidx[min(beg + j, Em1)];
        int cnt = min(dcnt - base, 8);
#pragma unroll
        for (int k = 0; k < 8; k++) {
            if (k < cnt) {
                int sv = __shfl(ss, gbase + k, 64);
                uint2 v = xq2[(size_t)sv * 8 + gl];
                float4 vA = fp8x4(v.x), vB = fp8x4(v.y);
                aA0.x += vA.x; aA0.y += vA.y; aA0.z += vA.z; aA0.w += vA.w;
                aB0.x += vB.x; aB0.y += vB.y; aB0.z += vB.z; aB0.w += vB.w;
            }
        }
    }
    if (i < N) {
        float4 oA, oB;
        oA.x = (aA0.x + aA1.x) * dis; oA.y = (aA0.y + aA1.y) * dis;
        oA.z = (aA0.z + aA1.z) * dis; oA.w = (aA0.w + aA1.w) * dis;
        oB.x = (aB0.x + aB1.x) * dis; oB.y = (aB0.y + aB1.y) * dis;
        oB.z = (aB0.z + aB1.z) * dis; oB.w = (aB0.w + aB1.w) * dis;
        float4* out = (float4*)(t1 + (size_t)i * F + gl * 8);
        out[0] = oA;
        out[1] = oB;
    }
}

// dense per-node dual GEMM: z2q = fp8(64 * (ReLU(gs*(t1@W1)+bias1)*dinv) @ w2l2)
__global__ __launch_bounds__(256, 2) void k_z(const float* __restrict__ t1,
                                              const int4* __restrict__ meta,
                                              const float* __restrict__ W1, const float* __restrict__ b1,
                                              const float* __restrict__ gamma, const float* __restrict__ beta,
                                              const float* __restrict__ w2l2, unsigned char* __restrict__ z2q, int N) {
    __shared__ __align__(16) unsigned short hb[4][F];  // bf16 h row per wave
    int tid = threadIdx.x, wave = tid >> 6, lane = tid & 63;
    int cc = lane & 31, khalf = lane >> 5;
    float gs = gamma[lane] * BN_INV;
    float bias1 = fmaf(b1[lane], gs, beta[lane]);
    float w1reg[F];
#pragma unroll
    for (int k = 0; k < F; k++) w1reg[k] = W1[k * F + lane] * gs;
    float w2reg[32];
#pragma unroll
    for (int j = 0; j < 32; j++) w2reg[j] = w2l2[(khalf * 32 + j) * OUTF + cc];

    for (int r = blockIdx.x * 4 + wave; r < N; r += gridDim.x * 4) {
        float di = __int_as_float(meta[r].z);
        const float4* trow = (const float4*)(t1 + (size_t)r * F);
        float o = bias1;
#pragma unroll
        for (int k4 = 0; k4 < 16; k4++) {
            float4 tv = trow[k4];  // all lanes same addr -> single 16B fetch
            o = fmaf(tv.x, w1reg[4 * k4 + 0], o);
            o = fmaf(tv.y, w1reg[4 * k4 + 1], o);
            o = fmaf(tv.z, w1reg[4 * k4 + 2], o);
            o = fmaf(tv.w, w1reg[4 * k4 + 3], o);
        }
        hb[wave][lane] = f2bf(fmaxf(o, 0.0f) * di);  // h (bf16)
        float z = 0.0f;
        const uint4* h4 = (const uint4*)&hb[wave][khalf * 32];
#pragma unroll
        for (int q = 0; q < 4; q++) {
            uint4 hv = h4[q];  // 8 bf16
            z = fmaf(bf2f((unsigned short)hv.x), w2reg[8 * q + 0], z);
            z = fmaf(bf2f((unsigned short)(hv.x >> 16)), w2reg[8 * q + 1], z);
            z = fmaf(bf2f((unsigned short)hv.y), w2reg[8 * q + 2], z);
            z = fmaf(bf2f((unsigned short)(hv.y >> 16)), w2reg[8 * q + 3], z);
            z = fmaf(bf2f((unsigned short)hv.z), w2reg[8 * q + 4], z);
            z = fmaf(bf2f((unsigned short)(hv.z >> 16)), w2reg[8 * q + 5], z);
            z = fmaf(bf2f((unsigned short)hv.w), w2reg[8 * q + 6], z);
            z = fmaf(bf2f((unsigned short)(hv.w >> 16)), w2reg[8 * q + 7], z);
        }
        z += __shfl_xor(z, 32, 64);  // combine halves (same cc)
        if (lane < 32) z2q[(size_t)r * OUTF + cc] = fp8enc1(z * ESC_Z);
    }
}

// conv2: gather of fp8 z2q (32 B rows, L2-resident). wave = 16 nodes x 4 lanes x 8ch.
// vbuf[24] uint2 burst + sched_barrier; logits bf16; fused softmax/entropy head.
__global__ __launch_bounds__(256, 4) void k_conv2agg(const uint2* __restrict__ z2q2,
                                                     const int4* __restrict__ meta,
                                                     const int* __restrict__ eidx, const float* __restrict__ b2l2,
                                                     unsigned short* __restrict__ logits_bf, float* __restrict__ wraw,
                                                     unsigned* __restrict__ redmm, int N, int Em1) {
    __shared__ float smn[4], smx[4];
    int tid = threadIdx.x, wave = tid >> 6, lane = tid & 63;
    int g = lane >> 2, gl = lane & 3, gbase = lane & 60;
    float4 bvA = ((const float4*)b2l2)[gl * 2];
    float4 bvB = ((const float4*)b2l2)[gl * 2 + 1];
    int i = (blockIdx.x * 4 + wave) * 16 + g;
    int iclamp = min(i, N - 1);
    int4 m = meta[iclamp];
    int beg = m.x;
    int dcnt = (i < N) ? m.y : 0;
    float dis = __int_as_float(m.z) * IESC_Z;
    int ss0 = eidx[min(beg + gl, Em1)];
    int ss1 = eidx[min(beg + 4 + gl, Em1)];
    int ss2 = eidx[min(beg + 8 + gl, Em1)];
    int ss3 = eidx[min(beg + 12 + gl, Em1)];
    int ss4 = eidx[min(beg + 16 + gl, Em1)];
    int ss5 = eidx[min(beg + 20 + gl, Em1)];
    uint2 selfv = z2q2[(size_t)iclamp * 4 + gl];
    uint2 vbuf[24];
#pragma unroll
    for (int k = 0; k < 24; k++) {
        int sreg = (k < 4) ? ss0 : (k < 8) ? ss1 : (k < 12) ? ss2 : (k < 16) ? ss3 : (k < 20) ? ss4 : ss5;
        int sv = __shfl(sreg, gbase + (k & 3), 64);
        sv = (k < dcnt) ? sv : iclamp;  // invalid slot -> own row (hot line)
        vbuf[k] = z2q2[(size_t)sv * 4 + gl];
    }
    __builtin_amdgcn_sched_barrier(0);  // pin: full burst before first use
    float4 aA0 = fp8x4(selfv.x), aB0 = fp8x4(selfv.y);
    if (i >= N) { aA0 = make_float4(0.f, 0.f, 0.f, 0.f); aB0 = aA0; }
    float4 aA1 = make_float4(0.f, 0.f, 0.f, 0.f), aB1 = aA1;
#pragma unroll
    for (int k = 0; k < 24; k++) {
        if (k < dcnt) {
            float4 vA = fp8x4(vbuf[k].x), vB = fp8x4(vbuf[k].y);
            if (k & 1) {
                aA1.x += vA.x; aA1.y += vA.y; aA1.z += vA.z; aA1.w += vA.w;
                aB1.x += vB.x; aB1.y += vB.y; aB1.z += vB.z; aB1.w += vB.w;
            } else {
                aA0.x += vA.x; aA0.y += vA.y; aA0.z += vA.z; aA0.w += vA.w;
                aB0.x += vB.x; aB0.y += vB.y; aB0.z += vB.z; aB0.w += vB.w;
            }
        }
    }
    for (int base = 24; base < dcnt; base += 4) {  // rare tail
        int j = base + gl;
        int ss = eidx[min(beg + j, Em1)];
        int cnt = min(dcnt - base, 4);
#pragma unroll
        for (int k = 0; k < 4; k++) {
            if (k < cnt) {
                int sv = __shfl(ss, gbase + k, 64);
                uint2 v = z2q2[(size_t)sv * 4 + gl];
                float4 vA = fp8x4(v.x), vB = fp8x4(v.y);
                aA0.x += vA.x; aA0.y += vA.y; aA0.z += vA.z; aA0.w += vA.w;
                aB0.x += vB.x; aB0.y += vB.y; aB0.z += vB.z; aB0.w += vB.w;
            }
        }
    }
    float4 lgA, lgB;
    lgA.x = fmaf(aA0.x + aA1.x, dis, bvA.x);
    lgA.y = fmaf(aA0.y + aA1.y, dis, bvA.y);
    lgA.z = fmaf(aA0.z + aA1.z, dis, bvA.z);
    lgA.w = fmaf(aA0.w + aA1.w, dis, bvA.w);
    lgB.x = fmaf(aB0.x + aB1.x, dis, bvB.x);
    lgB.y = fmaf(aB0.y + aB1.y, dis, bvB.y);
    lgB.z = fmaf(aB0.z + aB1.z, dis, bvB.z);
    lgB.w = fmaf(aB0.w + aB1.w, dis, bvB.w);
    if (i < N) {
        uint4 ob;
        ob.x = (unsigned)f2bf(lgA.x) | ((unsigned)f2bf(lgA.y) << 16);
        ob.y = (unsigned)f2bf(lgA.z) | ((unsigned)f2bf(lgA.w) << 16);
        ob.z = (unsigned)f2bf(lgB.x) | ((unsigned)f2bf(lgB.y) << 16);
        ob.w = (unsigned)f2bf(lgB.z) | ((unsigned)f2bf(lgB.w) << 16);
        *(uint4*)(logits_bf + (size_t)i * OUTF + gl * 8) = ob;
    }
    // softmax + entropy over 32 logits spread across 4 lanes x 8
    float m8 = fmaxf(fmaxf(fmaxf(lgA.x, lgA.y), fmaxf(lgA.z, lgA.w)),
                     fmaxf(fmaxf(lgB.x, lgB.y), fmaxf(lgB.z, lgB.w)));
    for (int off = 2; off > 0; off >>= 1) m8 = fmaxf(m8, __shfl_xor(m8, off, 4));
    float p0 = expf(lgA.x - m8), p1 = expf(lgA.y - m8), p2 = expf(lgA.z - m8), p3 = expf(lgA.w - m8);
    float p4 = expf(lgB.x - m8), p5 = expf(lgB.y - m8), p6 = expf(lgB.z - m8), p7 = expf(lgB.w - m8);
    float s8 = p0 + p1 + p2 + p3 + p4 + p5 + p6 + p7;
    for (int off = 2; off > 0; off >>= 1) s8 += __shfl_xor(s8, off, 4);
    float inv = 1.0f / s8;
    float t0 = p0 * inv, t1v = p1 * inv, t2v = p2 * inv, t3 = p3 * inv;
    float t4 = p4 * inv, t5 = p5 * inv, t6 = p6 * inv, t7 = p7 * inv;
    float e8 = t0 * logf(t0 + 1e-9f) + t1v * logf(t1v + 1e-9f) + t2v * logf(t2v + 1e-9f) + t3 * logf(t3 + 1e-9f) +
               t4 * logf(t4 + 1e-9f) + t5 * logf(t5 + 1e-9f) + t6 * logf(t6 + 1e-9f) + t7 * logf(t7 + 1e-9f);
    for (int off = 2; off > 0; off >>= 1) e8 += __shfl_xor(e8, off, 4);
    float w = 1.0f / (-e8 + 1e-10f);
    float mn = INFINITY, mx = -INFINITY;
    if (i < N) {
        if (gl == 0) wraw[i] = w;
        mn = w;
        mx = w;
    }
    for (int off = 32; off > 0; off >>= 1) {
        mn = fminf(mn, __shfl_xor(mn, off, 64));
        mx = fmaxf(mx, __shfl_xor(mx, off, 64));
    }
    if (lane == 0) { smn[wave] = mn; smx[wave] = mx; }
    __syncthreads();
    if (tid == 0) {
        float a = fminf(fminf(smn[0], smn[1]), fminf(smn[2], smn[3]));
        float b = fmaxf(fmaxf(smx[0], smx[1]), fmaxf(smx[2], smx[3]));
        atomicMin(&redmm[33], fenc(a));
        atomicMax(&redmm[34], fenc(b));
    }
}

__global__ __launch_bounds__(256) void k_weight(const unsigned short* __restrict__ logits_bf,
                                                const float* __restrict__ wraw,
                                                float* __restrict__ red, int N) {
    const unsigned* mm = (const unsigned*)red;
    float mn = fdec(mm[33]), mx = fdec(mm[34]);
    float inv = 1.0f / (mx - mn);
    int c = threadIdx.x & 31;
    int g = threadIdx.x >> 5;  // 8 row-groups
    float acc = 0.0f, es = 0.0f;
    for (int r = blockIdx.x * 8 + g; r < N; r += gridDim.x * 8) {
        float e = expf((wraw[r] - mn) * inv);
        acc += e * bf2f(logits_bf[(size_t)r * OUTF + c]);
        if (c == 0) es += e;
    }
    __shared__ float sa[8][OUTF];
    __shared__ float se[8];
    sa[g][c] = acc;
    if (c == 0) se[g] = es;
    __syncthreads();
    if (g == 0) {
        float t = sa[0][c];
#pragma unroll
        for (int i = 1; i < 8; i++) t += sa[i][c];
        unsafeAtomicAdd(&red[c], t);
        if (c == 0) {
            float u = 0.0f;
#pragma unroll
            for (int i = 0; i < 8; i++) u += se[i];
            unsafeAtomicAdd(&red[32], u);
        }
    }
}

__global__ void k_final(const float* __restrict__ red, const float* __restrict__ w3,
                        const float* __restrict__ b3, float* __restrict__ out) {
    int j = threadIdx.x;  // 64 threads
    float s = red[32];
    float o = b3[j];
#pragma unroll
    for (int cc = 0; cc < OUTF; cc++) o += (red[cc] / s) * w3[cc * F + j];
    out[j] = o;
}

extern "C" void kernel_launch(void* const* d_in, const int* in_sizes, int n_in,
                              void* d_out, int out_size, void* d_ws, size_t ws_size,
                              hipStream_t stream) {
    const float* x     = (const float*)d_in[0];
    const int*   ei    = (const int*)d_in[1];
    const float* W1    = (const float*)d_in[2];
    const float* b1    = (const float*)d_in[3];
    const float* gamma = (const float*)d_in[4];
    const float* beta  = (const float*)d_in[5];
    const float* W2    = (const float*)d_in[6];
    const float* b2    = (const float*)d_in[7];
    const float* l2w   = (const float*)d_in[8];
    const float* l2b   = (const float*)d_in[9];
    const float* l3w   = (const float*)d_in[10];
    const float* l3b   = (const float*)d_in[11];

    int N = in_sizes[0] / F;
    int E = in_sizes[1] / 2;
    const int* src = ei;
    const int* dst = ei + E;
    int NBK = (N + 255) >> 8;  // 391 buckets of 256 nodes (<=512 assumed)

    // workspace layout (16B-aligned chunks)
    char* p = (char*)d_ws;
    int* hist = (int*)p;                p += (size_t)PB * NBK * 4;
    int* btot = (int*)p;                p += 512 * 4;
    int* bbase = (int*)p;               p += 516 * 4;
    unsigned* bucketArr = (unsigned*)p; p += (size_t)E * 4;
    int4* meta = (int4*)p;              p += (size_t)N * 16;
    int* eidx = (int*)p;                p += (size_t)E * 4;
    float* red = (float*)p;             p += 64 * 4;
    float* w2l2 = (float*)p;            p += F * OUTF * 4;
    float* b2l2 = (float*)p;            p += OUTF * 4 + 32;
    unsigned* xq = (unsigned*)p;        p += (size_t)N * F;      // fp8, 64 B/row (aliased by z2q)
    float* t1 = (float*)p;              p += (size_t)N * F * 4;  // f32 (aliased by logits)
    float* wraw = (float*)p;            p += (size_t)N * 4;
    unsigned char* z2q = (unsigned char*)xq;       // xq dead after conv1agg; 32 B/row
    unsigned short* logits_bf = (unsigned short*)t1;  // t1 dead after k_z

    // setup + privatized counting-sort CSR build (fuse merged into hist grid)
    k_hist<<<PB + 8, 256, 0, stream>>>(dst, hist, E, NBK, W2, b2, l2w, l2b, w2l2, b2l2, red);
    k_hscan1<<<NBK, PB, 0, stream>>>(hist, btot, NBK);
    k_hscan2<<<1, 512, 0, stream>>>(btot, bbase, NBK);
    k_place<<<PB, 256, 0, stream>>>(src, dst, hist, bbase, bucketArr, E, NBK);
    k_binsort<<<NBK, 256, 0, stream>>>(bucketArr, bbase, eidx, meta, (const float4*)x, xq, N);

    // convs (exact-fit grids: one node-batch per wave)
    k_conv1agg<<<(N + 31) / 32, 256, 0, stream>>>((const uint2*)xq, meta, eidx, t1, N, E - 1);
    k_z<<<2048, 256, 0, stream>>>(t1, meta, W1, b1, gamma, beta, w2l2, z2q, N);  // 8 blocks/CU (was 4)
    k_conv2agg<<<(N + 63) / 64, 256, 0, stream>>>((const uint2*)z2q, meta, eidx, b2l2, logits_bf, wraw, (unsigned*)red, N, E - 1);

    // pooling head
    k_weight<<<2048, 256, 0, stream>>>(logits_bf, wraw, red, N);  // 8 blocks/CU (was 4)
    k_final<<<1, 64, 0, stream>>>(red, l3w, l3b, (float*)d_out);
}

// Round 17
// 310.176 us; speedup vs baseline: 1.1015x; 1.1015x over previous
//
#include <hip/hip_runtime.h>
#include <hip/hip_bf16.h>
#include <hip/hip_fp8.h>
#include <math.h>

// GCN. CSR via block-privatized 2-pass counting sort; fp8-e4m3 gathered arrays.
// r17: kill k_weight's atomic convoy — r16 PMC: 64us with VALU 3.5%/hbm 1% =
// 2048 blocks x 33 device-scope fp atomics onto ~3 cache lines (serialized at
// the coherence point; compute phase too short to stagger arrivals). Now each
// block writes private partials (part[blk*36+j], no atomics); k_final reduces
// 512x33 + does the lin3 GEMM. k_z stays at 2048 (r16 gain was real, masked).

#define F 64
#define OUTF 32
#define PB 128            // edge-partition blocks (privatized sort)
#define LEDGE 5632        // per-bucket LDS capacity (mean 4096)
#define WG 512            // k_weight blocks (each owns a 36-float partial slot)
#define BN_INV 0.9999950000374997f  // rsqrt(1 + 1e-5)
#define ESC_X 32.0f
#define IESC_X 0.03125f
#define ESC_Z 64.0f
#define IESC_Z 0.015625f

__device__ __forceinline__ unsigned fenc(float f) {
    unsigned u = __float_as_uint(f);
    return (u & 0x80000000u) ? ~u : (u | 0x80000000u);
}
__device__ __forceinline__ float fdec(unsigned e) {
    return (e & 0x80000000u) ? __uint_as_float(e & 0x7fffffffu) : __uint_as_float(~e);
}
__device__ __forceinline__ unsigned short f2bf(float f) {  // RNE
    unsigned u = __float_as_uint(f);
    return (unsigned short)((u + 0x7fffu + ((u >> 16) & 1u)) >> 16);
}
__device__ __forceinline__ float bf2f(unsigned short h) {
    return __uint_as_float((unsigned)h << 16);
}

#if __has_builtin(__builtin_amdgcn_cvt_f32_fp8) && __has_builtin(__builtin_amdgcn_cvt_pk_fp8_f32)
__device__ __forceinline__ float4 fp8x4(unsigned v) {
    return make_float4(__builtin_amdgcn_cvt_f32_fp8((int)v, 0),
                       __builtin_amdgcn_cvt_f32_fp8((int)v, 1),
                       __builtin_amdgcn_cvt_f32_fp8((int)v, 2),
                       __builtin_amdgcn_cvt_f32_fp8((int)v, 3));
}
__device__ __forceinline__ unsigned fp8pk4(float a, float b, float c, float d) {
    int r = __builtin_amdgcn_cvt_pk_fp8_f32(a, b, 0, false);
    r = __builtin_amdgcn_cvt_pk_fp8_f32(c, d, r, true);
    return (unsigned)r;
}
__device__ __forceinline__ unsigned char fp8enc1(float a) {
    return (unsigned char)(__builtin_amdgcn_cvt_pk_fp8_f32(a, a, 0, false) & 0xff);
}
#else
__device__ __forceinline__ float fp8d1(unsigned char b) {
    __hip_fp8_e4m3 v; v.__x = (__hip_fp8_storage_t)b; return (float)v;
}
__device__ __forceinline__ float4 fp8x4(unsigned v) {
    return make_float4(fp8d1(v & 255u), fp8d1((v >> 8) & 255u), fp8d1((v >> 16) & 255u), fp8d1((v >> 24) & 255u));
}
__device__ __forceinline__ unsigned char fp8enc1(float a) {
    return (unsigned char)__hip_fp8_e4m3(a).__x;
}
__device__ __forceinline__ unsigned fp8pk4(float a, float b, float c, float d) {
    return (unsigned)fp8enc1(a) | ((unsigned)fp8enc1(b) << 8) | ((unsigned)fp8enc1(c) << 16) | ((unsigned)fp8enc1(d) << 24);
}
#endif

// red layout: [33] min-enc(uint), [34] max-enc(uint)

// blocks 0..PB-1: histogram; blocks PB..PB+7: head-weight fusion + red init
__global__ __launch_bounds__(256) void k_hist(const int* __restrict__ dst, int* __restrict__ hist,
                                              int E, int NBK,
                                              const float* __restrict__ W2, const float* __restrict__ b2,
                                              const float* __restrict__ l2w, const float* __restrict__ l2b,
                                              float* __restrict__ w2l2, float* __restrict__ b2l2,
                                              float* __restrict__ red) {
    __shared__ int lh[512];
    int t = threadIdx.x, blk = blockIdx.x;
    if (blk >= PB) {  // fuse part
        int tt = (blk - PB) * 256 + t;  // 0..2047
        int k = tt >> 5, cc = tt & 31;
        float o = 0.0f;
        for (int j = 0; j < F; j++) o += W2[k * F + j] * l2w[j * OUTF + cc];
        w2l2[k * OUTF + cc] = o;
        if (tt < OUTF) {
            float b = l2b[tt];
            for (int j = 0; j < F; j++) b += b2[j] * l2w[j * OUTF + tt];
            b2l2[tt] = b;
        }
        if (tt == 33) ((unsigned*)red)[33] = 0xFFFFFFFFu;
        if (tt == 34) ((unsigned*)red)[34] = 0u;
        return;
    }
    for (int b = t; b < NBK; b += 256) lh[b] = 0;
    __syncthreads();
    int chunk = (E + PB - 1) / PB;
    int beg = blk * chunk, end = min(beg + chunk, E);
    for (int e = beg + t; e < end; e += 256) atomicAdd(&lh[dst[e] >> 8], 1);
    __syncthreads();
    for (int b = t; b < NBK; b += 256) hist[blk * NBK + b] = lh[b];  // dense coalesced
}

// per-bucket exclusive scan across the PB blocks (one block per bucket)
__global__ __launch_bounds__(PB) void k_hscan1(int* __restrict__ hist, int* __restrict__ btot, int NBK) {
    __shared__ int s[PB];
    int b = blockIdx.x, t = threadIdx.x;
    int v = hist[t * NBK + b];
    s[t] = v;
    __syncthreads();
    for (int off = 1; off < PB; off <<= 1) {
        int u = (t >= off) ? s[t - off] : 0;
        __syncthreads();
        s[t] += u;
        __syncthreads();
    }
    hist[t * NBK + b] = s[t] - v;  // exclusive within bucket
    if (t == PB - 1) btot[b] = s[t];
}

// scan bucket totals -> bbase (1 block; NBK <= 512)
__global__ void k_hscan2(const int* __restrict__ btot, int* __restrict__ bbase, int NBK) {
    __shared__ int s[512];
    int t = threadIdx.x;
    int v = (t < NBK) ? btot[t] : 0;
    s[t] = v;
    __syncthreads();
    for (int off = 1; off < 512; off <<= 1) {
        int u = (t >= off) ? s[t - off] : 0;
        __syncthreads();
        s[t] += u;
        __syncthreads();
    }
    if (t < NBK) {
        bbase[t] = s[t] - v;
        if (t == NBK - 1) bbase[NBK] = s[t];
    }
}

// pass 2: private cursors in LDS (hist offset + bucket base); single-writer lines
__global__ __launch_bounds__(256) void k_place(const int* __restrict__ src, const int* __restrict__ dst,
                                               const int* __restrict__ hist, const int* __restrict__ bbase,
                                               unsigned* __restrict__ bucketArr, int E, int NBK) {
    __shared__ int cur[512];
    int t = threadIdx.x, blk = blockIdx.x;
    for (int b = t; b < NBK; b += 256) cur[b] = hist[blk * NBK + b] + bbase[b];
    __syncthreads();
    int chunk = (E + PB - 1) / PB;
    int beg = blk * chunk, end = min(beg + chunk, E);
    for (int e = beg + t; e < end; e += 256) {
        int d = dst[e], sidx = src[e];
        int p = atomicAdd(&cur[d >> 8], 1);
        bucketArr[p] = ((unsigned)sidx << 8) | (unsigned)(d & 255);
    }
}

// one block per bucket: LDS count -> scan -> place -> fused x-prescale.
// Emits CSR eidx + meta{beg,deg,dinv} + xq = fp8(x*dinv*32).
__global__ __launch_bounds__(256) void k_binsort(const unsigned* __restrict__ bucketArr,
                                                 const int* __restrict__ bbase,
                                                 int* __restrict__ eidx, int4* __restrict__ meta,
                                                 const float4* __restrict__ x4, unsigned* __restrict__ xq, int N) {
    __shared__ unsigned ledge[LEDGE];
    __shared__ int lcnt[256], lofs[256], lcur[256], lscan[256];
    __shared__ float ldinv[256];
    int b = blockIdx.x, t = threadIdx.x;
    int gb = bbase[b];
    int count = min(bbase[b + 1] - gb, LEDGE);
    for (int j = t; j < count; j += 256) ledge[j] = bucketArr[gb + j];
    lcnt[t] = 0;
    __syncthreads();
    for (int j = t; j < count; j += 256) atomicAdd(&lcnt[ledge[j] & 255u], 1);
    __syncthreads();
    int deg = lcnt[t];
    lscan[t] = deg;
    __syncthreads();
    for (int off = 1; off < 256; off <<= 1) {
        int u = (t >= off) ? lscan[t - off] : 0;
        __syncthreads();
        lscan[t] += u;
        __syncthreads();
    }
    lofs[t] = lscan[t] - deg;  // exclusive
    lcur[t] = 0;
    int node = (b << 8) + t;
    float di = rsqrtf((float)deg + 1.0f);
    ldinv[t] = di;
    if (node < N) meta[node] = make_int4(gb + lofs[t], deg, __float_as_int(di), 0);
    __syncthreads();
    for (int j = t; j < count; j += 256) {
        unsigned v = ledge[j];
        int loc = (int)(v & 255u);
        int p = atomicAdd(&lcur[loc], 1);
        eidx[gb + lofs[loc] + p] = (int)(v >> 8);  // single-writer 16KB window
    }
    // fused prescale for this bucket's 256 nodes (coalesced: 16 threads/node)
    for (int idx = t; idx < 256 * 16; idx += 256) {
        int nd = (b << 8) + (idx >> 4);
        if (nd < N) {
            float d2 = ldinv[idx >> 4] * ESC_X;
            float4 v = x4[(size_t)nd * 16 + (idx & 15)];
            xq[(size_t)nd * 16 + (idx & 15)] = fp8pk4(v.x * d2, v.y * d2, v.z * d2, v.w * d2);
        }
    }
}

// conv1: t1 = f32( dinv/32 * (sum_nbr xq[s] + xq[i]) ).
// wave = 8 nodes x 8 lanes x 8ch (uint2 = 8 fp8 per lane). Exact-fit grid: 1 batch/wave.
__global__ __launch_bounds__(256, 4) void k_conv1agg(const uint2* __restrict__ xq2,
                                                     const int4* __restrict__ meta,
                                                     const int* __restrict__ eidx,
                                                     float* __restrict__ t1, int N, int Em1) {
    int tid = threadIdx.x, wave = tid >> 6, lane = tid & 63;
    int g = lane >> 3, gl = lane & 7, gbase = lane & 56;
    int i = (blockIdx.x * 4 + wave) * 8 + g;
    int iclamp = min(i, N - 1);
    int4 m = meta[iclamp];
    int beg = m.x;
    int dcnt = (i < N) ? m.y : 0;
    float dis = __int_as_float(m.z) * IESC_X;
    int ss0 = eidx[min(beg + gl, Em1)];
    int ss1 = eidx[min(beg + 8 + gl, Em1)];
    int ss2 = eidx[min(beg + 16 + gl, Em1)];
    int ss3 = eidx[min(beg + 24 + gl, Em1)];
    uint2 selfv = xq2[(size_t)iclamp * 8 + gl];
    uint2 vbuf[32];
#pragma unroll
    for (int k = 0; k < 32; k++) {
        int sreg = (k < 8) ? ss0 : (k < 16) ? ss1 : (k < 24) ? ss2 : ss3;
        int sv = __shfl(sreg, gbase + (k & 7), 64);
        sv = (k < dcnt) ? sv : iclamp;  // invalid slot -> own row (hot line)
        vbuf[k] = xq2[(size_t)sv * 8 + gl];
    }
    __builtin_amdgcn_sched_barrier(0);  // pin: full burst before first use
    float4 aA0 = fp8x4(selfv.x), aB0 = fp8x4(selfv.y);
    float4 aA1 = make_float4(0.f, 0.f, 0.f, 0.f), aB1 = aA1;
#pragma unroll
    for (int k = 0; k < 32; k++) {
        if (k < dcnt) {
            float4 vA = fp8x4(vbuf[k].x), vB = fp8x4(vbuf[k].y);
            if (k & 1) {
                aA1.x += vA.x; aA1.y += vA.y; aA1.z += vA.z; aA1.w += vA.w;
                aB1.x += vB.x; aB1.y += vB.y; aB1.z += vB.z; aB1.w += vB.w;
            } else {
                aA0.x += vA.x; aA0.y += vA.y; aA0.z += vA.z; aA0.w += vA.w;
                aB0.x += vB.x; aB0.y += vB.y; aB0.z += vB.z; aB0.w += vB.w;
            }
        }
    }
    for (int base = 32; base < dcnt; base += 8) {  // rare tail
        int j = base + gl;
        int ss = eidx[min(beg + j, Em1)];
        int cnt = min(dcnt - base, 8);
#pragma unroll
        for (int k = 0; k < 8; k++) {
            if (k < cnt) {
                int sv = __shfl(ss, gbase + k, 64);
                uint2 v = xq2[(size_t)sv * 8 + gl];
                float4 vA = fp8x4(v.x), vB = fp8x4(v.y);
                aA0.x += vA.x; aA0.y += vA.y; aA0.z += vA.z; aA0.w += vA.w;
                aB0.x += vB.x; aB0.y += vB.y; aB0.z += vB.z; aB0.w += vB.w;
            }
        }
    }
    if (i < N) {
        float4 oA, oB;
        oA.x = (aA0.x + aA1.x) * dis; oA.y = (aA0.y + aA1.y) * dis;
        oA.z = (aA0.z + aA1.z) * dis; oA.w = (aA0.w + aA1.w) * dis;
        oB.x = (aB0.x + aB1.x) * dis; oB.y = (aB0.y + aB1.y) * dis;
        oB.z = (aB0.z + aB1.z) * dis; oB.w = (aB0.w + aB1.w) * dis;
        float4* out = (float4*)(t1 + (size_t)i * F + gl * 8);
        out[0] = oA;
        out[1] = oB;
    }
}

// dense per-node dual GEMM: z2q = fp8(64 * (ReLU(gs*(t1@W1)+bias1)*dinv) @ w2l2)
__global__ __launch_bounds__(256, 2) void k_z(const float* __restrict__ t1,
                                              const int4* __restrict__ meta,
                                              const float* __restrict__ W1, const float* __restrict__ b1,
                                              const float* __restrict__ gamma, const float* __restrict__ beta,
                                              const float* __restrict__ w2l2, unsigned char* __restrict__ z2q, int N) {
    __shared__ __align__(16) unsigned short hb[4][F];  // bf16 h row per wave
    int tid = threadIdx.x, wave = tid >> 6, lane = tid & 63;
    int cc = lane & 31, khalf = lane >> 5;
    float gs = gamma[lane] * BN_INV;
    float bias1 = fmaf(b1[lane], gs, beta[lane]);
    float w1reg[F];
#pragma unroll
    for (int k = 0; k < F; k++) w1reg[k] = W1[k * F + lane] * gs;
    float w2reg[32];
#pragma unroll
    for (int j = 0; j < 32; j++) w2reg[j] = w2l2[(khalf * 32 + j) * OUTF + cc];

    for (int r = blockIdx.x * 4 + wave; r < N; r += gridDim.x * 4) {
        float di = __int_as_float(meta[r].z);
        const float4* trow = (const float4*)(t1 + (size_t)r * F);
        float o = bias1;
#pragma unroll
        for (int k4 = 0; k4 < 16; k4++) {
            float4 tv = trow[k4];  // all lanes same addr -> single 16B fetch
            o = fmaf(tv.x, w1reg[4 * k4 + 0], o);
            o = fmaf(tv.y, w1reg[4 * k4 + 1], o);
            o = fmaf(tv.z, w1reg[4 * k4 + 2], o);
            o = fmaf(tv.w, w1reg[4 * k4 + 3], o);
        }
        hb[wave][lane] = f2bf(fmaxf(o, 0.0f) * di);  // h (bf16)
        float z = 0.0f;
        const uint4* h4 = (const uint4*)&hb[wave][khalf * 32];
#pragma unroll
        for (int q = 0; q < 4; q++) {
            uint4 hv = h4[q];  // 8 bf16
            z = fmaf(bf2f((unsigned short)hv.x), w2reg[8 * q + 0], z);
            z = fmaf(bf2f((unsigned short)(hv.x >> 16)), w2reg[8 * q + 1], z);
            z = fmaf(bf2f((unsigned short)hv.y), w2reg[8 * q + 2], z);
            z = fmaf(bf2f((unsigned short)(hv.y >> 16)), w2reg[8 * q + 3], z);
            z = fmaf(bf2f((unsigned short)hv.z), w2reg[8 * q + 4], z);
            z = fmaf(bf2f((unsigned short)(hv.z >> 16)), w2reg[8 * q + 5], z);
            z = fmaf(bf2f((unsigned short)hv.w), w2reg[8 * q + 6], z);
            z = fmaf(bf2f((unsigned short)(hv.w >> 16)), w2reg[8 * q + 7], z);
        }
        z += __shfl_xor(z, 32, 64);  // combine halves (same cc)
        if (lane < 32) z2q[(size_t)r * OUTF + cc] = fp8enc1(z * ESC_Z);
    }
}

// conv2: gather of fp8 z2q (32 B rows, L2-resident). wave = 16 nodes x 4 lanes x 8ch.
// vbuf[24] uint2 burst + sched_barrier; logits bf16; fused softmax/entropy head.
__global__ __launch_bounds__(256, 4) void k_conv2agg(const uint2* __restrict__ z2q2,
                                                     const int4* __restrict__ meta,
                                                     const int* __restrict__ eidx, const float* __restrict__ b2l2,
                                                     unsigned short* __restrict__ logits_bf, float* __restrict__ wraw,
                                                     unsigned* __restrict__ redmm, int N, int Em1) {
    __shared__ float smn[4], smx[4];
    int tid = threadIdx.x, wave = tid >> 6, lane = tid & 63;
    int g = lane >> 2, gl = lane & 3, gbase = lane & 60;
    float4 bvA = ((const float4*)b2l2)[gl * 2];
    float4 bvB = ((const float4*)b2l2)[gl * 2 + 1];
    int i = (blockIdx.x * 4 + wave) * 16 + g;
    int iclamp = min(i, N - 1);
    int4 m = meta[iclamp];
    int beg = m.x;
    int dcnt = (i < N) ? m.y : 0;
    float dis = __int_as_float(m.z) * IESC_Z;
    int ss0 = eidx[min(beg + gl, Em1)];
    int ss1 = eidx[min(beg + 4 + gl, Em1)];
    int ss2 = eidx[min(beg + 8 + gl, Em1)];
    int ss3 = eidx[min(beg + 12 + gl, Em1)];
    int ss4 = eidx[min(beg + 16 + gl, Em1)];
    int ss5 = eidx[min(beg + 20 + gl, Em1)];
    uint2 selfv = z2q2[(size_t)iclamp * 4 + gl];
    uint2 vbuf[24];
#pragma unroll
    for (int k = 0; k < 24; k++) {
        int sreg = (k < 4) ? ss0 : (k < 8) ? ss1 : (k < 12) ? ss2 : (k < 16) ? ss3 : (k < 20) ? ss4 : ss5;
        int sv = __shfl(sreg, gbase + (k & 3), 64);
        sv = (k < dcnt) ? sv : iclamp;  // invalid slot -> own row (hot line)
        vbuf[k] = z2q2[(size_t)sv * 4 + gl];
    }
    __builtin_amdgcn_sched_barrier(0);  // pin: full burst before first use
    float4 aA0 = fp8x4(selfv.x), aB0 = fp8x4(selfv.y);
    if (i >= N) { aA0 = make_float4(0.f, 0.f, 0.f, 0.f); aB0 = aA0; }
    float4 aA1 = make_float4(0.f, 0.f, 0.f, 0.f), aB1 = aA1;
#pragma unroll
    for (int k = 0; k < 24; k++) {
        if (k < dcnt) {
            float4 vA = fp8x4(vbuf[k].x), vB = fp8x4(vbuf[k].y);
            if (k & 1) {
                aA1.x += vA.x; aA1.y += vA.y; aA1.z += vA.z; aA1.w += vA.w;
                aB1.x += vB.x; aB1.y += vB.y; aB1.z += vB.z; aB1.w += vB.w;
            } else {
                aA0.x += vA.x; aA0.y += vA.y; aA0.z += vA.z; aA0.w += vA.w;
                aB0.x += vB.x; aB0.y += vB.y; aB0.z += vB.z; aB0.w += vB.w;
            }
        }
    }
    for (int base = 24; base < dcnt; base += 4) {  // rare tail
        int j = base + gl;
        int ss = eidx[min(beg + j, Em1)];
        int cnt = min(dcnt - base, 4);
#pragma unroll
        for (int k = 0; k < 4; k++) {
            if (k < cnt) {
                int sv = __shfl(ss, gbase + k, 64);
                uint2 v = z2q2[(size_t)sv * 4 + gl];
                float4 vA = fp8x4(v.x), vB = fp8x4(v.y);
                aA0.x += vA.x; aA0.y += vA.y; aA0.z += vA.z; aA0.w += vA.w;
                aB0.x += vB.x; aB0.y += vB.y; aB0.z += vB.z; aB0.w += vB.w;
            }
        }
    }
    float4 lgA, lgB;
    lgA.x = fmaf(aA0.x + aA1.x, dis, bvA.x);
    lgA.y = fmaf(aA0.y + aA1.y, dis, bvA.y);
    lgA.z = fmaf(aA0.z + aA1.z, dis, bvA.z);
    lgA.w = fmaf(aA0.w + aA1.w, dis, bvA.w);
    lgB.x = fmaf(aB0.x + aB1.x, dis, bvB.x);
    lgB.y = fmaf(aB0.y + aB1.y, dis, bvB.y);
    lgB.z = fmaf(aB0.z + aB1.z, dis, bvB.z);
    lgB.w = fmaf(aB0.w + aB1.w, dis, bvB.w);
    if (i < N) {
        uint4 ob;
        ob.x = (unsigned)f2bf(lgA.x) | ((unsigned)f2bf(lgA.y) << 16);
        ob.y = (unsigned)f2bf(lgA.z) | ((unsigned)f2bf(lgA.w) << 16);
        ob.z = (unsigned)f2bf(lgB.x) | ((unsigned)f2bf(lgB.y) << 16);
        ob.w = (unsigned)f2bf(lgB.z) | ((unsigned)f2bf(lgB.w) << 16);
        *(uint4*)(logits_bf + (size_t)i * OUTF + gl * 8) = ob;
    }
    // softmax + entropy over 32 logits spread across 4 lanes x 8
    float m8 = fmaxf(fmaxf(fmaxf(lgA.x, lgA.y), fmaxf(lgA.z, lgA.w)),
                     fmaxf(fmaxf(lgB.x, lgB.y), fmaxf(lgB.z, lgB.w)));
    for (int off = 2; off > 0; off >>= 1) m8 = fmaxf(m8, __shfl_xor(m8, off, 4));
    float p0 = expf(lgA.x - m8), p1 = expf(lgA.y - m8), p2 = expf(lgA.z - m8), p3 = expf(lgA.w - m8);
    float p4 = expf(lgB.x - m8), p5 = expf(lgB.y - m8), p6 = expf(lgB.z - m8), p7 = expf(lgB.w - m8);
    float s8 = p0 + p1 + p2 + p3 + p4 + p5 + p6 + p7;
    for (int off = 2; off > 0; off >>= 1) s8 += __shfl_xor(s8, off, 4);
    float inv = 1.0f / s8;
    float t0 = p0 * inv, t1v = p1 * inv, t2v = p2 * inv, t3 = p3 * inv;
    float t4 = p4 * inv, t5 = p5 * inv, t6 = p6 * inv, t7 = p7 * inv;
    float e8 = t0 * logf(t0 + 1e-9f) + t1v * logf(t1v + 1e-9f) + t2v * logf(t2v + 1e-9f) + t3 * logf(t3 + 1e-9f) +
               t4 * logf(t4 + 1e-9f) + t5 * logf(t5 + 1e-9f) + t6 * logf(t6 + 1e-9f) + t7 * logf(t7 + 1e-9f);
    for (int off = 2; off > 0; off >>= 1) e8 += __shfl_xor(e8, off, 4);
    float w = 1.0f / (-e8 + 1e-10f);
    float mn = INFINITY, mx = -INFINITY;
    if (i < N) {
        if (gl == 0) wraw[i] = w;
        mn = w;
        mx = w;
    }
    for (int off = 32; off > 0; off >>= 1) {
        mn = fminf(mn, __shfl_xor(mn, off, 64));
        mx = fmaxf(mx, __shfl_xor(mx, off, 64));
    }
    if (lane == 0) { smn[wave] = mn; smx[wave] = mx; }
    __syncthreads();
    if (tid == 0) {
        float a = fminf(fminf(smn[0], smn[1]), fminf(smn[2], smn[3]));
        float b = fmaxf(fmaxf(smx[0], smx[1]), fmaxf(smx[2], smx[3]));
        atomicMin(&redmm[33], fenc(a));
        atomicMax(&redmm[34], fenc(b));
    }
}

// weighted sum partials: block blk writes part[blk*36 + {0..31, 32}] — no atomics
__global__ __launch_bounds__(256) void k_weight(const unsigned short* __restrict__ logits_bf,
                                                const float* __restrict__ wraw,
                                                const float* __restrict__ red,
                                                float* __restrict__ part, int N) {
    const unsigned* mm = (const unsigned*)red;
    float mn = fdec(mm[33]), mx = fdec(mm[34]);
    float inv = 1.0f / (mx - mn);
    int c = threadIdx.x & 31;
    int g = threadIdx.x >> 5;  // 8 row-groups
    float acc = 0.0f, es = 0.0f;
    for (int r = blockIdx.x * 8 + g; r < N; r += gridDim.x * 8) {
        float e = expf((wraw[r] - mn) * inv);
        acc += e * bf2f(logits_bf[(size_t)r * OUTF + c]);
        if (c == 0) es += e;
    }
    __shared__ float sa[8][OUTF];
    __shared__ float se[8];
    sa[g][c] = acc;
    if (c == 0) se[g] = es;
    __syncthreads();
    if (g == 0) {
        float t = sa[0][c];
#pragma unroll
        for (int i = 1; i < 8; i++) t += sa[i][c];
        part[blockIdx.x * 36 + c] = t;  // private slot, plain store
        if (c == 0) {
            float u = 0.0f;
#pragma unroll
            for (int i = 0; i < 8; i++) u += se[i];
            part[blockIdx.x * 36 + 32] = u;
        }
    }
}

// reduce WG x 33 partials + final 1x32 @ 32x64 GEMM
__global__ __launch_bounds__(256) void k_final(const float* __restrict__ part,
                                               const float* __restrict__ w3, const float* __restrict__ b3,
                                               float* __restrict__ out) {
    __shared__ float sa[8][OUTF];
    __shared__ float se[8];
    __shared__ float facc[OUTF + 1];
    int tid = threadIdx.x;
    int g = tid >> 5, c = tid & 31;
    float acc = 0.0f, es = 0.0f;
    for (int p = g; p < WG; p += 8) {
        acc += part[p * 36 + c];
        if (c == 0) es += part[p * 36 + 32];
    }
    sa[g][c] = acc;
    if (c == 0) se[g] = es;
    __syncthreads();
    if (tid < OUTF) {
        float t = 0.0f;
#pragma unroll
        for (int i = 0; i < 8; i++) t += sa[i][tid];
        facc[tid] = t;
    }
    if (tid == 32) {
        float u = 0.0f;
#pragma unroll
        for (int i = 0; i < 8; i++) u += se[i];
        facc[OUTF] = u;
    }
    __syncthreads();
    if (tid < F) {
        float s = facc[OUTF];
        float o = b3[tid];
#pragma unroll
        for (int cc = 0; cc < OUTF; cc++) o += (facc[cc] / s) * w3[cc * F + tid];
        out[tid] = o;
    }
}

extern "C" void kernel_launch(void* const* d_in, const int* in_sizes, int n_in,
                              void* d_out, int out_size, void* d_ws, size_t ws_size,
                              hipStream_t stream) {
    const float* x     = (const float*)d_in[0];
    const int*   ei    = (const int*)d_in[1];
    const float* W1    = (const float*)d_in[2];
    const float* b1    = (const float*)d_in[3];
    const float* gamma = (const float*)d_in[4];
    const float* beta  = (const float*)d_in[5];
    const float* W2    = (const float*)d_in[6];
    const float* b2    = (const float*)d_in[7];
    const float* l2w   = (const float*)d_in[8];
    const float* l2b   = (const float*)d_in[9];
    const float* l3w   = (const float*)d_in[10];
    const float* l3b   = (const float*)d_in[11];

    int N = in_sizes[0] / F;
    int E = in_sizes[1] / 2;
    const int* src = ei;
    const int* dst = ei + E;
    int NBK = (N + 255) >> 8;  // 391 buckets of 256 nodes (<=512 assumed)

    // workspace layout (16B-aligned chunks)
    char* p = (char*)d_ws;
    int* hist = (int*)p;                p += (size_t)PB * NBK * 4;
    int* btot = (int*)p;                p += 512 * 4;
    int* bbase = (int*)p;               p += 516 * 4;
    unsigned* bucketArr = (unsigned*)p; p += (size_t)E * 4;
    int4* meta = (int4*)p;              p += (size_t)N * 16;
    int* eidx = (int*)p;                p += (size_t)E * 4;
    float* red = (float*)p;             p += 64 * 4;
    float* part = (float*)p;            p += (size_t)WG * 36 * 4;
    float* w2l2 = (float*)p;            p += F * OUTF * 4;
    float* b2l2 = (float*)p;            p += OUTF * 4 + 32;
    unsigned* xq = (unsigned*)p;        p += (size_t)N * F;      // fp8, 64 B/row (aliased by z2q)
    float* t1 = (float*)p;              p += (size_t)N * F * 4;  // f32 (aliased by logits)
    float* wraw = (float*)p;            p += (size_t)N * 4;
    unsigned char* z2q = (unsigned char*)xq;       // xq dead after conv1agg; 32 B/row
    unsigned short* logits_bf = (unsigned short*)t1;  // t1 dead after k_z

    // setup + privatized counting-sort CSR build (fuse merged into hist grid)
    k_hist<<<PB + 8, 256, 0, stream>>>(dst, hist, E, NBK, W2, b2, l2w, l2b, w2l2, b2l2, red);
    k_hscan1<<<NBK, PB, 0, stream>>>(hist, btot, NBK);
    k_hscan2<<<1, 512, 0, stream>>>(btot, bbase, NBK);
    k_place<<<PB, 256, 0, stream>>>(src, dst, hist, bbase, bucketArr, E, NBK);
    k_binsort<<<NBK, 256, 0, stream>>>(bucketArr, bbase, eidx, meta, (const float4*)x, xq, N);

    // convs (exact-fit grids: one node-batch per wave)
    k_conv1agg<<<(N + 31) / 32, 256, 0, stream>>>((const uint2*)xq, meta, eidx, t1, N, E - 1);
    k_z<<<2048, 256, 0, stream>>>(t1, meta, W1, b1, gamma, beta, w2l2, z2q, N);
    k_conv2agg<<<(N + 63) / 64, 256, 0, stream>>>((const uint2*)z2q, meta, eidx, b2l2, logits_bf, wraw, (unsigned*)red, N, E - 1);

    // pooling head (atomic-free partials -> merged reduce+GEMM)
    k_weight<<<WG, 256, 0, stream>>>(logits_bf, wraw, red, part, N);
    k_final<<<1, 256, 0, stream>>>(part, l3w, l3b, (float*)d_out);
}